// Round 2
// baseline (299.874 us; speedup 1.0000x reference)
//
#include <hip/hip_runtime.h>

// SelfTensorProductS2Grid via bf16 MFMA (16x16x32):
//   grid[g,c] = sum_i Wt[g,i] X[i,c];  out[i,c] = sum_g Wf[g,i] grid[g,c]^2
// g is an internal contraction index -> relabeled so stage-1's C/D layout
// IS stage-2's B-operand layout (permutation baked into WfF prep).
//
// v4 vs v3 (104 us, spill-bound): v3's __launch_bounds__(1024,4) capped the
// unified VGPR+AGPR file at 128/wave -> 64 arch VGPRs -> ~136 B/thread scratch
// (FETCH/WRITE both +35 MB). Fix: no min-waves cap (occupancy is LDS-limited
// to 1 block/CU = 16 waves = 50% anyway). Also back to c-half tasks (v2
// granularity): halves LDS read traffic and per-wave overhead vs c-quarter.
// Keeps v3's wins: W fragments in LDS (no L2 round-trips, 0 bank conflicts),
// v_cvt_pk_bf16_f32 for all fp32->bf16.

#define NN    4096
#define L2D   49
#define CCH   128
#define GTOT  324
#define MT1P  22              // stage-1 g-tiles of 16 (21 real + 1 zero pad)
#define KC2   11              // stage-2 g-chunks of 32

typedef __attribute__((ext_vector_type(8))) short bf16x8;
typedef __attribute__((ext_vector_type(4))) float f32x4;

#define WT_SHORTS (MT1P * 2 * 64 * 8)   // 22528
#define WF_SHORTS (4 * KC2 * 64 * 8)    // 22528
#define W_SHORTS  (WT_SHORTS + WF_SHORTS)

__device__ __forceinline__ short f2bf(float f) {
    union { float f; unsigned u; } x; x.f = f;
    return (short)((x.u + 0x7fffu + ((x.u >> 16) & 1u)) >> 16);   // RNE
}

// pack two f32 -> two bf16 (RNE) in one VALU op
__device__ __forceinline__ unsigned cvtpk(float lo, float hi) {
    unsigned r;
    asm("v_cvt_pk_bf16_f32 %0, %1, %2" : "=v"(r) : "v"(lo), "v"(hi));
    return r;
}

// WtF[mt][kcx][lane][j]: A[m=g=mt*16+(lane&15)][k=i=kcx*32+(lane>>4)*8+j]
// WfF[it][kc2][lane][j]: A[m=i=it*16+(lane&15)][k=glog], where
//   gphys(glog) = kc2*32 + (j>>2)*16 + (lane>>4)*4 + (j&3)   <-- the relabel
__global__ void prep_w_kernel(const float* __restrict__ Wt,
                              const float* __restrict__ Wf,
                              short* __restrict__ WtF,
                              short* __restrict__ WfF)
{
    int idx = blockIdx.x * 256 + threadIdx.x;
    if (idx < WT_SHORTS) {
        int j = idx & 7, lane = (idx >> 3) & 63, kcx = (idx >> 9) & 1, mt = idx >> 10;
        int g = mt * 16 + (lane & 15);
        int i = kcx * 32 + (lane >> 4) * 8 + j;
        WtF[idx] = f2bf((g < GTOT && i < L2D) ? Wt[g * L2D + i] : 0.0f);
    } else if (idx < WT_SHORTS + WF_SHORTS) {
        int e = idx - WT_SHORTS;
        int j = e & 7, lane = (e >> 3) & 63, t = e >> 9;
        int kc2 = t % KC2, it = t / KC2;
        int i = it * 16 + (lane & 15);
        int g = kc2 * 32 + (j >> 2) * 16 + (lane >> 4) * 4 + (j & 3);
        WfF[e] = f2bf((g < GTOT && i < L2D) ? Wf[g * L2D + i] : 0.0f);
    }
}

__global__ __launch_bounds__(1024)
void stp_mfma4_kernel(const float* __restrict__ inp,
                      const short* __restrict__ Wbase,
                      float* __restrict__ out)
{
    __shared__ __attribute__((aligned(16))) short sW[W_SHORTS];

    const int tid = threadIdx.x;

    // ---- cooperative LDS fill of all W fragments (contiguous 90112 B) ----
    {
        const uint4* __restrict__ src = (const uint4*)Wbase;
        uint4* dst = (uint4*)sW;
        #pragma unroll
        for (int e = 0; e < 6; ++e) {
            int idx = tid + e * 1024;
            if (idx < W_SHORTS / 8) dst[idx] = src[idx];
        }
    }
    __syncthreads();

    const int lane = tid & 63;
    const int wave = tid >> 6;       // 0..15
    const int lm   = lane & 15;
    const int quad = lane >> 4;
    const int h    = wave & 1;       // c-half: c in [h*64, h*64+64)
    const int nw   = wave >> 1;      // n sub-index 0..7

    const short* sWt = sW;
    const short* sWf = sW + WT_SHORTS;

    for (int rep = 0; rep < 2; ++rep) {
        const int n = blockIdx.x * 16 + rep * 8 + nw;
        const float* __restrict__ Xn = inp + (size_t)n * (L2D * CCH);

        // ---- X B-fragments from global: B[k=i][n=c] ----
        // lane holds c = h*64 + t*16 + lm ; i = kcx*32 + quad*8 + j
        bf16x8 Bx[4][2];
        #pragma unroll
        for (int t = 0; t < 4; ++t) {
            const int c = h * 64 + t * 16 + lm;
            #pragma unroll
            for (int kcx = 0; kcx < 2; ++kcx) {
                union { bf16x8 v; unsigned u[4]; } b;
                #pragma unroll
                for (int p = 0; p < 4; ++p) {
                    const int i0 = kcx * 32 + quad * 8 + 2 * p;
                    float v0 = (i0     < L2D) ? Xn[(i0    ) * CCH + c] : 0.0f;
                    float v1 = (i0 + 1 < L2D) ? Xn[(i0 + 1) * CCH + c] : 0.0f;
                    b.u[p] = cvtpk(v0, v1);
                }
                Bx[t][kcx] = b.v;
            }
        }

        f32x4 acc2[4][4];
        #pragma unroll
        for (int it = 0; it < 4; ++it)
            #pragma unroll
            for (int t = 0; t < 4; ++t)
                acc2[it][t] = (f32x4){0.0f, 0.0f, 0.0f, 0.0f};

        #pragma unroll 1
        for (int kc2 = 0; kc2 < KC2; ++kc2) {
            // W fragments for this g-chunk, from LDS (conflict-free b128)
            bf16x8 Wtf[2][2];
            #pragma unroll
            for (int tt = 0; tt < 2; ++tt)
                #pragma unroll
                for (int kcx = 0; kcx < 2; ++kcx)
                    Wtf[tt][kcx] = *(const bf16x8*)&sWt[(((2 * kc2 + tt) * 2 + kcx) * 64 + lane) * 8];
            bf16x8 Wff[4];
            #pragma unroll
            for (int it = 0; it < 4; ++it)
                Wff[it] = *(const bf16x8*)&sWf[((it * KC2 + kc2) * 64 + lane) * 8];

            #pragma unroll
            for (int t = 0; t < 4; ++t) {
                // stage 1: two 16-row g-tiles -> C-layout regs = B-frag halves
                union { bf16x8 v; unsigned u[4]; } bg;
                #pragma unroll
                for (int tt = 0; tt < 2; ++tt) {
                    f32x4 g = (f32x4){0.0f, 0.0f, 0.0f, 0.0f};
                    g = __builtin_amdgcn_mfma_f32_16x16x32_bf16(Wtf[tt][0], Bx[t][0], g, 0, 0, 0);
                    g = __builtin_amdgcn_mfma_f32_16x16x32_bf16(Wtf[tt][1], Bx[t][1], g, 0, 0, 0);
                    bg.u[tt * 2 + 0] = cvtpk(g[0] * g[0], g[1] * g[1]);
                    bg.u[tt * 2 + 1] = cvtpk(g[2] * g[2], g[3] * g[3]);
                }
                // stage 2: accumulate out[i, c] over this g-chunk
                #pragma unroll
                for (int it = 0; it < 4; ++it)
                    acc2[it][t] = __builtin_amdgcn_mfma_f32_16x16x32_bf16(Wff[it], bg.v, acc2[it][t], 0, 0, 0);
            }
        }

        // ---- store: C/D layout col=c=lm, row=i=it*16+quad*4+r ----
        float* __restrict__ On = out + (size_t)n * (L2D * CCH);
        #pragma unroll
        for (int it = 0; it < 4; ++it) {
            #pragma unroll
            for (int t = 0; t < 4; ++t) {
                const int c = h * 64 + t * 16 + lm;
                #pragma unroll
                for (int r = 0; r < 4; ++r) {
                    const int i = it * 16 + quad * 4 + r;
                    if (i < L2D) On[i * CCH + c] = acc2[it][t][r];
                }
            }
        }
    }
}

extern "C" void kernel_launch(void* const* d_in, const int* in_sizes, int n_in,
                              void* d_out, int out_size, void* d_ws, size_t ws_size,
                              hipStream_t stream) {
    const float* inp = (const float*)d_in[0];   // (4096, 49, 128) fp32
    const float* Wt  = (const float*)d_in[1];   // (18*18, 49) fp32
    const float* Wf  = (const float*)d_in[2];   // (18*18, 49) fp32
    float* out = (float*)d_out;                 // (4096, 49, 128) fp32

    short* WtF = (short*)d_ws;
    short* WfF = WtF + WT_SHORTS;               // total 90112 B of ws

    const int prep_threads = WT_SHORTS + WF_SHORTS;   // 45056
    prep_w_kernel<<<(prep_threads + 255) / 256, 256, 0, stream>>>(Wt, Wf, WtF, WfF);
    stp_mfma4_kernel<<<256, 1024, 0, stream>>>(inp, (const short*)WtF, out);
}

// Round 3
// 217.029 us; speedup vs baseline: 1.3817x; 1.3817x over previous
//
#include <hip/hip_runtime.h>

// SelfTensorProductS2Grid via bf16 MFMA (16x16x32):
//   grid[g,c] = sum_i Wt[g,i] X[i,c];  out[i,c] = sum_g Wf[g,i] grid[g,c]^2
// g is an internal contraction index -> relabeled so stage-1's C/D layout
// IS stage-2's B-operand layout (permutation baked into WfF prep).
//
// v5: back to 256-thread blocks (v3/v4 lesson: a 1024-thread block forces
// 4 waves/SIMD at launch -> 128-reg unified budget -> guaranteed spill;
// VGPR pool is ~512/SIMD). v2's latency source (8 W loads from L2 at the
// top of every kc2 iteration, consumed immediately) is attacked within the
// 3-blocks/CU register budget (170/wave):
//  - WfF (45 KB) staged in LDS once per block: 3 x 45 KB = 135 KB <= 160 KB
//    keeps 3 blocks/CU; Wff reads become ~120-cyc conflict-free ds_read_b128.
//  - WtF software-pipelined: kc2+1's 4 fragments prefetched into regs at the
//    top of iteration kc2; the reg copy after the MFMAs places the waitcnt
//    after compute, hiding L2 latency under the 24 MFMAs.
//  - keeps v3's v_cvt_pk_bf16_f32 everywhere (1 op / 2 elems).

#define NN    4096
#define L2D   49
#define CCH   128
#define GTOT  324
#define MT1P  22              // stage-1 g-tiles of 16 (21 real + 1 zero pad)
#define KC2   11              // stage-2 g-chunks of 32

typedef __attribute__((ext_vector_type(8))) short bf16x8;
typedef __attribute__((ext_vector_type(4))) float f32x4;

#define WT_SHORTS (MT1P * 2 * 64 * 8)   // 22528
#define WF_SHORTS (4 * KC2 * 64 * 8)    // 22528

__device__ __forceinline__ short f2bf(float f) {
    union { float f; unsigned u; } x; x.f = f;
    return (short)((x.u + 0x7fffu + ((x.u >> 16) & 1u)) >> 16);   // RNE
}

// pack two f32 -> two bf16 (RNE) in one VALU op
__device__ __forceinline__ unsigned cvtpk(float lo, float hi) {
    unsigned r;
    asm("v_cvt_pk_bf16_f32 %0, %1, %2" : "=v"(r) : "v"(lo), "v"(hi));
    return r;
}

// WtF[mt][kcx][lane][j]: A[m=g=mt*16+(lane&15)][k=i=kcx*32+(lane>>4)*8+j]
// WfF[it][kc2][lane][j]: A[m=i=it*16+(lane&15)][k=glog], where
//   gphys(glog) = kc2*32 + (j>>2)*16 + (lane>>4)*4 + (j&3)   <-- the relabel
__global__ void prep_w_kernel(const float* __restrict__ Wt,
                              const float* __restrict__ Wf,
                              short* __restrict__ WtF,
                              short* __restrict__ WfF)
{
    int idx = blockIdx.x * 256 + threadIdx.x;
    if (idx < WT_SHORTS) {
        int j = idx & 7, lane = (idx >> 3) & 63, kcx = (idx >> 9) & 1, mt = idx >> 10;
        int g = mt * 16 + (lane & 15);
        int i = kcx * 32 + (lane >> 4) * 8 + j;
        WtF[idx] = f2bf((g < GTOT && i < L2D) ? Wt[g * L2D + i] : 0.0f);
    } else if (idx < WT_SHORTS + WF_SHORTS) {
        int e = idx - WT_SHORTS;
        int j = e & 7, lane = (e >> 3) & 63, t = e >> 9;
        int kc2 = t % KC2, it = t / KC2;
        int i = it * 16 + (lane & 15);
        int g = kc2 * 32 + (j >> 2) * 16 + (lane >> 4) * 4 + (j & 3);
        WfF[e] = f2bf((g < GTOT && i < L2D) ? Wf[g * L2D + i] : 0.0f);
    }
}

__global__ __launch_bounds__(256, 3)
void stp_mfma5_kernel(const float* __restrict__ inp,
                      const short* __restrict__ WtF,
                      const short* __restrict__ WfF,
                      float* __restrict__ out)
{
    __shared__ __attribute__((aligned(16))) short sWf[WF_SHORTS];

    const int tid  = threadIdx.x;

    // ---- cooperative LDS fill of WfF (45056 B = 2816 uint4 = 11 x 256) ----
    {
        const uint4* __restrict__ src = (const uint4*)WfF;
        uint4* dst = (uint4*)sWf;
        #pragma unroll
        for (int e = 0; e < 11; ++e)
            dst[tid + e * 256] = src[tid + e * 256];
    }
    __syncthreads();

    const int lane = tid & 63;
    const int wave = tid >> 6;
    const int lm   = lane & 15;
    const int quad = lane >> 4;

    const int task = blockIdx.x * 4 + wave;   // 8192 tasks = (n, c-half)
    const int n    = task >> 1;
    const int h    = task & 1;

    const float* __restrict__ Xn = inp + (size_t)n * (L2D * CCH);

    // ---- X B-fragments straight from global: B[k=i][n=c] ----
    // lane holds c = h*64 + t*16 + lm ; i = kcx*32 + quad*8 + j
    bf16x8 Bx[4][2];
    #pragma unroll
    for (int t = 0; t < 4; ++t) {
        const int c = h * 64 + t * 16 + lm;
        #pragma unroll
        for (int kcx = 0; kcx < 2; ++kcx) {
            union { bf16x8 v; unsigned u[4]; } b;
            #pragma unroll
            for (int p = 0; p < 4; ++p) {
                const int i0 = kcx * 32 + quad * 8 + 2 * p;
                float v0 = (i0     < L2D) ? Xn[(i0    ) * CCH + c] : 0.0f;
                float v1 = (i0 + 1 < L2D) ? Xn[(i0 + 1) * CCH + c] : 0.0f;
                b.u[p] = cvtpk(v0, v1);
            }
            Bx[t][kcx] = b.v;
        }
    }

    f32x4 acc2[4][4];
    #pragma unroll
    for (int it = 0; it < 4; ++it)
        #pragma unroll
        for (int t = 0; t < 4; ++t)
            acc2[it][t] = (f32x4){0.0f, 0.0f, 0.0f, 0.0f};

    // prime the WtF pipeline with kc2 = 0
    bf16x8 WtfC[2][2];
    #pragma unroll
    for (int tt = 0; tt < 2; ++tt)
        #pragma unroll
        for (int kcx = 0; kcx < 2; ++kcx)
            WtfC[tt][kcx] = *(const bf16x8*)&WtF[((tt * 2 + kcx) * 64 + lane) * 8];

    #pragma unroll 1
    for (int kc2 = 0; kc2 < KC2; ++kc2) {
        // prefetch next iteration's WtF fragments (L2-resident, 4 x 16 B)
        const int kn = (kc2 + 1 < KC2) ? kc2 + 1 : kc2;
        bf16x8 WtfN[2][2];
        #pragma unroll
        for (int tt = 0; tt < 2; ++tt)
            #pragma unroll
            for (int kcx = 0; kcx < 2; ++kcx)
                WtfN[tt][kcx] = *(const bf16x8*)&WtF[(((2 * kn + tt) * 2 + kcx) * 64 + lane) * 8];

        // WfF fragments from LDS (conflict-free contiguous b128)
        bf16x8 Wff[4];
        #pragma unroll
        for (int it = 0; it < 4; ++it)
            Wff[it] = *(const bf16x8*)&sWf[((it * KC2 + kc2) * 64 + lane) * 8];

        #pragma unroll
        for (int t = 0; t < 4; ++t) {
            // stage 1: two 16-row g-tiles -> C-layout regs = B-frag halves
            union { bf16x8 v; unsigned u[4]; } bg;
            #pragma unroll
            for (int tt = 0; tt < 2; ++tt) {
                f32x4 g = (f32x4){0.0f, 0.0f, 0.0f, 0.0f};
                g = __builtin_amdgcn_mfma_f32_16x16x32_bf16(WtfC[tt][0], Bx[t][0], g, 0, 0, 0);
                g = __builtin_amdgcn_mfma_f32_16x16x32_bf16(WtfC[tt][1], Bx[t][1], g, 0, 0, 0);
                bg.u[tt * 2 + 0] = cvtpk(g[0] * g[0], g[1] * g[1]);
                bg.u[tt * 2 + 1] = cvtpk(g[2] * g[2], g[3] * g[3]);
            }
            // stage 2: accumulate out[i, c] over this g-chunk
            #pragma unroll
            for (int it = 0; it < 4; ++it)
                acc2[it][t] = __builtin_amdgcn_mfma_f32_16x16x32_bf16(Wff[it], bg.v, acc2[it][t], 0, 0, 0);
        }

        // rotate pipeline: waitcnt for these loads lands here, after compute
        #pragma unroll
        for (int tt = 0; tt < 2; ++tt)
            #pragma unroll
            for (int kcx = 0; kcx < 2; ++kcx)
                WtfC[tt][kcx] = WtfN[tt][kcx];
    }

    // ---- store: C/D layout col=c=lm, row=i=it*16+quad*4+r ----
    float* __restrict__ On = out + (size_t)n * (L2D * CCH);
    #pragma unroll
    for (int it = 0; it < 4; ++it) {
        #pragma unroll
        for (int t = 0; t < 4; ++t) {
            const int c = h * 64 + t * 16 + lm;
            #pragma unroll
            for (int r = 0; r < 4; ++r) {
                const int i = it * 16 + quad * 4 + r;
                if (i < L2D) On[i * CCH + c] = acc2[it][t][r];
            }
        }
    }
}

extern "C" void kernel_launch(void* const* d_in, const int* in_sizes, int n_in,
                              void* d_out, int out_size, void* d_ws, size_t ws_size,
                              hipStream_t stream) {
    const float* inp = (const float*)d_in[0];   // (4096, 49, 128) fp32
    const float* Wt  = (const float*)d_in[1];   // (18*18, 49) fp32
    const float* Wf  = (const float*)d_in[2];   // (18*18, 49) fp32
    float* out = (float*)d_out;                 // (4096, 49, 128) fp32

    short* WtF = (short*)d_ws;
    short* WfF = WtF + WT_SHORTS;               // total 90112 B of ws

    const int prep_threads = WT_SHORTS + WF_SHORTS;   // 45056
    prep_w_kernel<<<(prep_threads + 255) / 256, 256, 0, stream>>>(Wt, Wf, WtF, WfF);
    stp_mfma5_kernel<<<2048, 256, 0, stream>>>(inp, WtF, WfF, out);
}